// Round 5
// baseline (104.329 us; speedup 1.0000x reference)
//
#include <hip/hip_runtime.h>

#define D_FEAT 128
#define NPB 40           // nodes per block (250 blocks for 10000 nodes)
#define QCAP 192         // per-node LDS queue capacity (Poisson(64) max ~115)
#define THREADS 1024     // 16 waves/block -> 4 waves/SIMD at 1 block/CU
#define MAX_OVF 4096

typedef unsigned short u16;
typedef u16 ushort8_t __attribute__((ext_vector_type(8)));

// Kernel A: compress dst (int32) -> u16. Coalesced int4 read, ushort4 write.
__global__ void dst16_kernel(const int* __restrict__ dst, u16* __restrict__ d16,
                             int n) {
    int i = blockIdx.x * blockDim.x + threadIdx.x;  // handles 4 elements
    int base = i * 4;
    if (base + 3 < n) {
        int4 v = ((const int4*)dst)[i];
        ushort4 o;
        o.x = (u16)v.x; o.y = (u16)v.y; o.z = (u16)v.z; o.w = (u16)v.w;
        ((ushort4*)d16)[i] = o;
    } else if (base < n) {
        for (int k = base; k < n; ++k) d16[k] = (u16)dst[k];
    }
}

// Kernel B: fused build+gather. Block owns node range [bstart, bstart+NPB).
// Phase 1: stream all dst16, append in-range edges' src ids to per-node LDS
// queues. Phase 2: per-wave register gather from LDS queue, normalize, write.
__global__ __launch_bounds__(THREADS) void fused_kernel(
        const float* __restrict__ feat, const int* __restrict__ src,
        const u16* __restrict__ d16, float* __restrict__ out,
        int* __restrict__ cnt_global, int* __restrict__ ovf_cnt,
        int* __restrict__ ovf, int n_nodes, int n_edges) {
    __shared__ int scnt[NPB];
    __shared__ int sq[NPB * QCAP];   // 40*192*4 = 30 KB

    int tid = threadIdx.x;
    int bstart = blockIdx.x * NPB;
    int lo = bstart;
    int hi = bstart + NPB; if (hi > n_nodes) hi = n_nodes;

    if (tid < NPB) scnt[tid] = 0;
    __syncthreads();

    // ---- Phase 1: scan all edges (8 per 16B load), 1-deep prefetch ----
    int packs = (n_edges + 7) >> 3;
    const ushort8_t* dp = (const ushort8_t*)d16;
    int p = tid;
    ushort8_t cur = {};
    if (p < packs) cur = dp[p];
    while (p < packs) {
        int pn = p + THREADS;
        ushort8_t nxt = {};
        if (pn < packs) nxt = dp[pn];
        #pragma unroll
        for (int k = 0; k < 8; ++k) {
            int d = cur[k];
            if (d >= lo && d < hi) {
                int e = p * 8 + k;
                if (e < n_edges) {
                    int s = src[e];
                    int dl = d - lo;
                    int pos = atomicAdd(&scnt[dl], 1);
                    if (pos < QCAP) {
                        sq[dl * QCAP + pos] = s;
                    } else {
                        int o = atomicAdd(ovf_cnt, 1);
                        if (o < MAX_OVF) { ovf[2 * o] = s; ovf[2 * o + 1] = d; }
                    }
                }
            }
        }
        cur = nxt;
        p = pn;
    }
    __syncthreads();

    // ---- Phase 2: wave w gathers nodes w, w+16, ... of this block ----
    int wave = tid >> 6;
    int lane = tid & 63;
    const float2* f2 = (const float2*)feat;   // 64 float2 per row
    for (int ln = wave; ln < NPB; ln += (THREADS / 64)) {
        int node = bstart + ln;
        if (node >= n_nodes) break;
        int full = scnt[ln];
        int degq = full < QCAP ? full : QCAP;
        const int* q = &sq[ln * QCAP];
        float2 a0 = {0.f, 0.f}, a1 = {0.f, 0.f};
        float2 a2 = {0.f, 0.f}, a3 = {0.f, 0.f};
        int i = 0;
        for (; i + 4 <= degq; i += 4) {
            int4 s4 = *(const int4*)&q[i];     // wave-uniform -> LDS broadcast
            float2 v0 = f2[(size_t)s4.x * 64 + lane];
            float2 v1 = f2[(size_t)s4.y * 64 + lane];
            float2 v2 = f2[(size_t)s4.z * 64 + lane];
            float2 v3 = f2[(size_t)s4.w * 64 + lane];
            a0.x += v0.x; a0.y += v0.y;
            a1.x += v1.x; a1.y += v1.y;
            a2.x += v2.x; a2.y += v2.y;
            a3.x += v3.x; a3.y += v3.y;
        }
        for (; i < degq; ++i) {
            int s = q[i];
            float2 v = f2[(size_t)s * 64 + lane];
            a0.x += v.x; a0.y += v.y;
        }
        float2 r;
        r.x = (a0.x + a1.x) + (a2.x + a3.x);
        r.y = (a0.y + a1.y) + (a2.y + a3.y);
        float sc = rsqrtf((float)(full > 1 ? full : 1));
        r.x *= sc; r.y *= sc;
        ((float2*)out)[(size_t)node * 64 + lane] = r;
        if (lane == 0) cnt_global[node] = full;
    }
}

// Handle LDS-queue overflow edges (expected: none). Adds normalized
// contributions on top of fused kernel's output.
__global__ void patch_kernel(const float* __restrict__ feat,
                             const int* __restrict__ cnt,
                             const int* __restrict__ ovf_cnt,
                             const int* __restrict__ ovf,
                             float* __restrict__ out) {
    int novf = *ovf_cnt;
    if (novf > MAX_OVF) novf = MAX_OVF;
    long long total  = (long long)novf * D_FEAT;
    long long stride = (long long)gridDim.x * blockDim.x;
    for (long long i = (long long)blockIdx.x * blockDim.x + threadIdx.x;
         i < total; i += stride) {
        int o = (int)(i >> 7);
        int f = (int)(i & 127);
        int s = ovf[2 * o];
        int d = ovf[2 * o + 1];
        int dgi = cnt[d]; if (dgi < 1) dgi = 1;
        float v = feat[(long long)s * D_FEAT + f] * rsqrtf((float)dgi);
        atomicAdd(&out[(long long)d * D_FEAT + f], v);
    }
}

// ---------------- fallback path (fp32 atomics, no ws assumptions) ----------

__global__ void zero_kernel(float* __restrict__ out, float* __restrict__ deg,
                            int n_out, int n_deg) {
    int i = blockIdx.x * blockDim.x + threadIdx.x;
    if (i < n_out) out[i] = 0.0f;
    if (i < n_deg) deg[i] = 0.0f;
}

__global__ void scatter_kernel(const float* __restrict__ feat,
                               const int* __restrict__ src,
                               const int* __restrict__ dst,
                               float* __restrict__ out,
                               float* __restrict__ deg,
                               int n_edges) {
    long long gid = (long long)blockIdx.x * blockDim.x + threadIdx.x;
    int e = (int)(gid >> 7);
    int f = (int)(gid & 127);
    if (e >= n_edges) return;
    int s = src[e];
    int d = dst[e];
    float v = feat[(long long)s * D_FEAT + f];
    atomicAdd(&out[(long long)d * D_FEAT + f], v);
    if (f == 0) atomicAdd(&deg[d], 1.0f);
}

__global__ void norm_kernel(float* __restrict__ out, const float* __restrict__ deg,
                            int n_out) {
    int gid = blockIdx.x * blockDim.x + threadIdx.x;
    if (gid >= n_out) return;
    int i = gid >> 7;
    float dg = fmaxf(deg[i], 1.0f);
    out[gid] = out[gid] * rsqrtf(dg);
}

extern "C" void kernel_launch(void* const* d_in, const int* in_sizes, int n_in,
                              void* d_out, int out_size, void* d_ws, size_t ws_size,
                              hipStream_t stream) {
    const float* feat = (const float*)d_in[0];
    const int*   src  = (const int*)d_in[1];
    const int*   dst  = (const int*)d_in[2];
    float* out = (float*)d_out;

    const int n_edges = in_sizes[1];
    const int n_out   = out_size;            // n_nodes * 128
    const int n_nodes = n_out / D_FEAT;

    // ws layout: d16[packs*8 u16] | ovf_cnt[1]+pad[3] | ovf[2*MAX_OVF] | cnt[n_nodes]
    int packs = (n_edges + 7) >> 3;
    size_t d16_bytes = (size_t)packs * 8 * sizeof(u16);
    d16_bytes = (d16_bytes + 15) & ~(size_t)15;   // align
    size_t need = d16_bytes + (size_t)(4 + 2 * MAX_OVF + n_nodes) * sizeof(int);

    if (ws_size >= need && n_nodes <= 65535) {
        u16* d16     = (u16*)d_ws;
        int* ovf_cnt = (int*)((char*)d_ws + d16_bytes);
        int* ovf     = ovf_cnt + 4;
        int* cntg    = ovf + 2 * MAX_OVF;

        hipMemsetAsync(ovf_cnt, 0, 4 * sizeof(int), stream);
        {
            int work = (n_edges + 3) / 4;
            int threads = 256;
            int blocks = (work + threads - 1) / threads;
            dst16_kernel<<<blocks, threads, 0, stream>>>(dst, d16, n_edges);
        }
        {
            int blocks = (n_nodes + NPB - 1) / NPB;
            fused_kernel<<<blocks, THREADS, 0, stream>>>(
                feat, src, d16, out, cntg, ovf_cnt, ovf, n_nodes, n_edges);
        }
        patch_kernel<<<32, 256, 0, stream>>>(feat, cntg, ovf_cnt, ovf, out);
    } else {
        float* deg = (float*)d_ws;
        {
            int threads = 256;
            int blocks = (n_out + threads - 1) / threads;
            zero_kernel<<<blocks, threads, 0, stream>>>(out, deg, n_out, n_nodes);
        }
        {
            long long total = (long long)n_edges * D_FEAT;
            int threads = 256;
            int blocks = (int)((total + threads - 1) / threads);
            scatter_kernel<<<blocks, threads, 0, stream>>>(feat, src, dst, out, deg, n_edges);
        }
        {
            int threads = 256;
            int blocks = (n_out + threads - 1) / threads;
            norm_kernel<<<blocks, threads, 0, stream>>>(out, deg, n_out);
        }
    }
}

// Round 6
// 57.798 us; speedup vs baseline: 1.8051x; 1.8051x over previous
//
#include <hip/hip_runtime.h>

#define D_FEAT 128
#define NPP 16            // nodes per partition (p = d >> 4)
#define QCAP 128          // per-node LDS queue capacity (Poisson(64): P(>128)~5e-13)
#define MAX_NPART 4096    // supports n_nodes <= 65536
#define MAX_OVF 8192
#define EPB 4096          // edges per bin_kernel block (1024 thr x 4)

// ---------------- Kernel 1: partitioned binning ----------------
// Block handles a 4096-edge slice. Per-partition rank via LDS atomics, one
// global cursor reservation per (block, partition), then rank-dense packed
// writes (coalescer merges same-line lanes). pack = (d&15)<<27 | s.
__global__ __launch_bounds__(1024) void bin_kernel(
        const int* __restrict__ src, const int* __restrict__ dst,
        int* __restrict__ gcur, int* __restrict__ ovf_cnt,
        int* __restrict__ ovf, int* __restrict__ ovf_deg,
        unsigned int* __restrict__ bins,
        int n_edges, int npart, int cap_seg) {
    __shared__ int lcnt[MAX_NPART];
    __shared__ int lbase[MAX_NPART];
    int tid = threadIdx.x;
    for (int i = tid; i < npart; i += blockDim.x) lcnt[i] = 0;
    __syncthreads();

    int e4 = blockIdx.x * blockDim.x + tid;
    int be = e4 * 4;
    int s0 = 0, s1 = 0, s2 = 0, s3 = 0, d0 = -1, d1 = -1, d2 = -1, d3 = -1;
    if (be + 3 < n_edges) {
        int4 sv = ((const int4*)src)[e4];
        int4 dv = ((const int4*)dst)[e4];
        s0 = sv.x; s1 = sv.y; s2 = sv.z; s3 = sv.w;
        d0 = dv.x; d1 = dv.y; d2 = dv.z; d3 = dv.w;
    } else if (be < n_edges) {
        if (be + 0 < n_edges) { s0 = src[be + 0]; d0 = dst[be + 0]; }
        if (be + 1 < n_edges) { s1 = src[be + 1]; d1 = dst[be + 1]; }
        if (be + 2 < n_edges) { s2 = src[be + 2]; d2 = dst[be + 2]; }
        if (be + 3 < n_edges) { s3 = src[be + 3]; d3 = dst[be + 3]; }
    }
    int p0 = d0 >> 4, p1 = d1 >> 4, p2 = d2 >> 4, p3 = d3 >> 4;
    int r0 = 0, r1 = 0, r2 = 0, r3 = 0;
    if (d0 >= 0) r0 = atomicAdd(&lcnt[p0], 1);
    if (d1 >= 0) r1 = atomicAdd(&lcnt[p1], 1);
    if (d2 >= 0) r2 = atomicAdd(&lcnt[p2], 1);
    if (d3 >= 0) r3 = atomicAdd(&lcnt[p3], 1);
    __syncthreads();
    for (int i = tid; i < npart; i += blockDim.x)
        if (lcnt[i] > 0) lbase[i] = atomicAdd(&gcur[i], lcnt[i]);
    __syncthreads();

    #define EMIT(dK, sK, pK, rK)                                              \
        if (dK >= 0) {                                                        \
            int idx = lbase[pK] + rK;                                         \
            unsigned int pk = ((unsigned int)(dK & (NPP - 1)) << 27) |        \
                              (unsigned int)sK;                               \
            if (idx < cap_seg) {                                              \
                bins[(size_t)pK * cap_seg + idx] = pk;                        \
            } else {                                                          \
                int o = atomicAdd(ovf_cnt, 1);                                \
                if (o < MAX_OVF) { ovf[2 * o] = sK; ovf[2 * o + 1] = dK; }    \
                atomicAdd(&ovf_deg[dK], 1);                                   \
            }                                                                 \
        }
    EMIT(d0, s0, p0, r0)
    EMIT(d1, s1, p1, r1)
    EMIT(d2, s2, p2, r2)
    EMIT(d3, s3, p3, r3)
    #undef EMIT
}

// ---------------- Kernel 2: per-partition queue build + gather ----------------
// Block p: read own segment (coalesced), bin into 16 per-node LDS queues,
// then wave-gather feat rows, normalize, write each output row once.
__global__ __launch_bounds__(256) void gather_part_kernel(
        const float* __restrict__ feat, const unsigned int* __restrict__ bins,
        const int* __restrict__ gcur, int* __restrict__ ovf_cnt,
        int* __restrict__ ovf, int* __restrict__ deg_io,
        float* __restrict__ out, int n_nodes, int cap_seg) {
    __shared__ int sq[NPP * QCAP];   // 16*128*4 = 8 KB
    __shared__ int scnt[NPP];
    int tid = threadIdx.x;
    int p = blockIdx.x;
    int bstart = p * NPP;
    if (tid < NPP) scnt[tid] = 0;
    __syncthreads();

    int cnt = gcur[p];
    if (cnt > cap_seg) cnt = cap_seg;
    const unsigned int* seg = bins + (size_t)p * cap_seg;
    for (int i = tid; i < cnt; i += blockDim.x) {
        unsigned int pk = seg[i];
        int dl = (int)(pk >> 27);
        int s  = (int)(pk & 0x7FFFFFFu);
        int pos = atomicAdd(&scnt[dl], 1);
        if (pos < QCAP) {
            sq[dl * QCAP + pos] = s;
        } else {
            int o = atomicAdd(ovf_cnt, 1);
            if (o < MAX_OVF) { ovf[2 * o] = s; ovf[2 * o + 1] = bstart + dl; }
        }
    }
    __syncthreads();

    int wave = tid >> 6;
    int lane = tid & 63;
    const float2* f2 = (const float2*)feat;   // 64 float2 per row
    for (int ln = wave; ln < NPP; ln += 4) {
        int node = bstart + ln;
        if (node >= n_nodes) break;
        int full = scnt[ln] + deg_io[node];    // + segment-overflow edges
        int degq = scnt[ln] < QCAP ? scnt[ln] : QCAP;
        const int* q = &sq[ln * QCAP];
        float2 a0 = {0.f, 0.f}, a1 = {0.f, 0.f};
        float2 a2 = {0.f, 0.f}, a3 = {0.f, 0.f};
        int i = 0;
        for (; i + 4 <= degq; i += 4) {
            int4 s4 = *(const int4*)&q[i];     // wave-uniform LDS broadcast
            float2 v0 = f2[(size_t)s4.x * 64 + lane];
            float2 v1 = f2[(size_t)s4.y * 64 + lane];
            float2 v2 = f2[(size_t)s4.z * 64 + lane];
            float2 v3 = f2[(size_t)s4.w * 64 + lane];
            a0.x += v0.x; a0.y += v0.y;
            a1.x += v1.x; a1.y += v1.y;
            a2.x += v2.x; a2.y += v2.y;
            a3.x += v3.x; a3.y += v3.y;
        }
        for (; i < degq; ++i) {
            int s = q[i];
            float2 v = f2[(size_t)s * 64 + lane];
            a0.x += v.x; a0.y += v.y;
        }
        float2 r;
        r.x = (a0.x + a1.x) + (a2.x + a3.x);
        r.y = (a0.y + a1.y) + (a2.y + a3.y);
        float sc = rsqrtf((float)(full > 1 ? full : 1));
        r.x *= sc; r.y *= sc;
        ((float2*)out)[(size_t)node * 64 + lane] = r;
        if (lane == 0) deg_io[node] = full;    // final degree for patch
    }
}

// Overflow edges (expected: none). deg_io holds final degrees.
__global__ void patch_kernel(const float* __restrict__ feat,
                             const int* __restrict__ deg_io,
                             const int* __restrict__ ovf_cnt,
                             const int* __restrict__ ovf,
                             float* __restrict__ out) {
    int novf = *ovf_cnt;
    if (novf > MAX_OVF) novf = MAX_OVF;
    long long total  = (long long)novf * D_FEAT;
    long long stride = (long long)gridDim.x * blockDim.x;
    for (long long i = (long long)blockIdx.x * blockDim.x + threadIdx.x;
         i < total; i += stride) {
        int o = (int)(i >> 7);
        int f = (int)(i & 127);
        int s = ovf[2 * o];
        int d = ovf[2 * o + 1];
        int dgi = deg_io[d]; if (dgi < 1) dgi = 1;
        float v = feat[(long long)s * D_FEAT + f] * rsqrtf((float)dgi);
        atomicAdd(&out[(long long)d * D_FEAT + f], v);
    }
}

// ---------------- fallback path (fp32 atomics) ----------------

__global__ void zero_kernel(float* __restrict__ out, float* __restrict__ deg,
                            int n_out, int n_deg) {
    int i = blockIdx.x * blockDim.x + threadIdx.x;
    if (i < n_out) out[i] = 0.0f;
    if (i < n_deg) deg[i] = 0.0f;
}

__global__ void scatter_kernel(const float* __restrict__ feat,
                               const int* __restrict__ src,
                               const int* __restrict__ dst,
                               float* __restrict__ out,
                               float* __restrict__ deg,
                               int n_edges) {
    long long gid = (long long)blockIdx.x * blockDim.x + threadIdx.x;
    int e = (int)(gid >> 7);
    int f = (int)(gid & 127);
    if (e >= n_edges) return;
    int s = src[e];
    int d = dst[e];
    float v = feat[(long long)s * D_FEAT + f];
    atomicAdd(&out[(long long)d * D_FEAT + f], v);
    if (f == 0) atomicAdd(&deg[d], 1.0f);
}

__global__ void norm_kernel(float* __restrict__ out, const float* __restrict__ deg,
                            int n_out) {
    int gid = blockIdx.x * blockDim.x + threadIdx.x;
    if (gid >= n_out) return;
    int i = gid >> 7;
    float dg = fmaxf(deg[i], 1.0f);
    out[gid] = out[gid] * rsqrtf(dg);
}

extern "C" void kernel_launch(void* const* d_in, const int* in_sizes, int n_in,
                              void* d_out, int out_size, void* d_ws, size_t ws_size,
                              hipStream_t stream) {
    const float* feat = (const float*)d_in[0];
    const int*   src  = (const int*)d_in[1];
    const int*   dst  = (const int*)d_in[2];
    float* out = (float*)d_out;

    const int n_edges = in_sizes[1];
    const int n_out   = out_size;            // n_nodes * 128
    const int n_nodes = n_out / D_FEAT;

    int npart = (n_nodes + NPP - 1) / NPP;
    // segment capacity: mean + 8*sigma + slack, rounded to 16
    int avg = n_edges / (npart > 0 ? npart : 1);
    int cap_seg = avg + 8 * (int)sqrtf((float)(avg > 0 ? avg : 1)) + 64;
    cap_seg = (cap_seg + 15) & ~15;

    // ws layout (ints): gcur[npart] | ovf_cnt[1]+pad[3] | deg[n_nodes]
    //                   | ovf[2*MAX_OVF] | bins[npart*cap_seg]
    size_t zero_ints = (size_t)npart + 4 + n_nodes;
    size_t need = (zero_ints + 2 * MAX_OVF + (size_t)npart * cap_seg) * sizeof(int);

    if (ws_size >= need && npart <= MAX_NPART && n_nodes <= (1 << 27)) {
        int* gcur    = (int*)d_ws;
        int* ovf_cnt = gcur + npart;
        int* deg_io  = ovf_cnt + 4;
        int* ovf     = deg_io + n_nodes;
        unsigned int* bins = (unsigned int*)(ovf + 2 * MAX_OVF);

        hipMemsetAsync(d_ws, 0, zero_ints * sizeof(int), stream);
        {
            int blocks = (n_edges + EPB - 1) / EPB;
            bin_kernel<<<blocks, 1024, 0, stream>>>(
                src, dst, gcur, ovf_cnt, ovf, deg_io, bins,
                n_edges, npart, cap_seg);
        }
        gather_part_kernel<<<npart, 256, 0, stream>>>(
            feat, bins, gcur, ovf_cnt, ovf, deg_io, out, n_nodes, cap_seg);
        patch_kernel<<<32, 256, 0, stream>>>(feat, deg_io, ovf_cnt, ovf, out);
    } else {
        float* deg = (float*)d_ws;
        {
            int threads = 256;
            int blocks = (n_out + threads - 1) / threads;
            zero_kernel<<<blocks, threads, 0, stream>>>(out, deg, n_out, n_nodes);
        }
        {
            long long total = (long long)n_edges * D_FEAT;
            int threads = 256;
            int blocks = (int)((total + threads - 1) / threads);
            scatter_kernel<<<blocks, threads, 0, stream>>>(feat, src, dst, out, deg, n_edges);
        }
        {
            int threads = 256;
            int blocks = (n_out + threads - 1) / threads;
            norm_kernel<<<blocks, threads, 0, stream>>>(out, deg, n_out);
        }
    }
}

// Round 7
// 55.627 us; speedup vs baseline: 1.8755x; 1.0390x over previous
//
#include <hip/hip_runtime.h>

#define D_FEAT 128
#define NPP 16            // nodes per partition (p = d >> 4)
#define QCAP 128          // per-node LDS queue capacity (Poisson(64): P(>128)~5e-13)
#define MAX_NPART 4096    // supports n_nodes <= 65536
#define MAX_OVF 8192
#define EPB 4096          // edges per bin_kernel block (1024 thr x 4)

// ---------------- Kernel 0: zero the control workspace ----------------
__global__ void zero_ws_kernel(int* __restrict__ p, int n) {
    int i = blockIdx.x * blockDim.x + threadIdx.x;
    if (i < n) p[i] = 0;
}

// ---------------- Kernel 1: partitioned binning ----------------
// Block handles a 4096-edge slice. Per-partition rank via LDS atomics, one
// global cursor reservation per (block, partition), then rank-dense packed
// writes (coalescer merges same-line lanes). pack = (d&15)<<27 | s.
__global__ __launch_bounds__(1024) void bin_kernel(
        const int* __restrict__ src, const int* __restrict__ dst,
        int* __restrict__ gcur, int* __restrict__ ovf_cnt,
        int* __restrict__ ovf, int* __restrict__ ovf_deg,
        unsigned int* __restrict__ bins,
        int n_edges, int npart, int cap_seg) {
    __shared__ int lcnt[MAX_NPART];
    __shared__ int lbase[MAX_NPART];
    int tid = threadIdx.x;
    for (int i = tid; i < npart; i += blockDim.x) lcnt[i] = 0;
    __syncthreads();

    int e4 = blockIdx.x * blockDim.x + tid;
    int be = e4 * 4;
    int s0 = 0, s1 = 0, s2 = 0, s3 = 0, d0 = -1, d1 = -1, d2 = -1, d3 = -1;
    if (be + 3 < n_edges) {
        int4 sv = ((const int4*)src)[e4];
        int4 dv = ((const int4*)dst)[e4];
        s0 = sv.x; s1 = sv.y; s2 = sv.z; s3 = sv.w;
        d0 = dv.x; d1 = dv.y; d2 = dv.z; d3 = dv.w;
    } else if (be < n_edges) {
        if (be + 0 < n_edges) { s0 = src[be + 0]; d0 = dst[be + 0]; }
        if (be + 1 < n_edges) { s1 = src[be + 1]; d1 = dst[be + 1]; }
        if (be + 2 < n_edges) { s2 = src[be + 2]; d2 = dst[be + 2]; }
        if (be + 3 < n_edges) { s3 = src[be + 3]; d3 = dst[be + 3]; }
    }
    int p0 = d0 >> 4, p1 = d1 >> 4, p2 = d2 >> 4, p3 = d3 >> 4;
    int r0 = 0, r1 = 0, r2 = 0, r3 = 0;
    if (d0 >= 0) r0 = atomicAdd(&lcnt[p0], 1);
    if (d1 >= 0) r1 = atomicAdd(&lcnt[p1], 1);
    if (d2 >= 0) r2 = atomicAdd(&lcnt[p2], 1);
    if (d3 >= 0) r3 = atomicAdd(&lcnt[p3], 1);
    __syncthreads();
    for (int i = tid; i < npart; i += blockDim.x)
        if (lcnt[i] > 0) lbase[i] = atomicAdd(&gcur[i], lcnt[i]);
    __syncthreads();

    #define EMIT(dK, sK, pK, rK)                                              \
        if (dK >= 0) {                                                        \
            int idx = lbase[pK] + rK;                                         \
            unsigned int pk = ((unsigned int)(dK & (NPP - 1)) << 27) |        \
                              (unsigned int)sK;                               \
            if (idx < cap_seg) {                                              \
                bins[(size_t)pK * cap_seg + idx] = pk;                        \
            } else {                                                          \
                int o = atomicAdd(ovf_cnt, 1);                                \
                if (o < MAX_OVF) { ovf[2 * o] = sK; ovf[2 * o + 1] = dK; }    \
                atomicAdd(&ovf_deg[dK], 1);                                   \
            }                                                                 \
        }
    EMIT(d0, s0, p0, r0)
    EMIT(d1, s1, p1, r1)
    EMIT(d2, s2, p2, r2)
    EMIT(d3, s3, p3, r3)
    #undef EMIT
}

// ---------------- Kernel 2: per-partition queue build + gather ----------------
// Block p: read own segment (coalesced), bin into 16 per-node LDS queues,
// then wave-gather feat rows, normalize, write each output row once.
__global__ __launch_bounds__(256) void gather_part_kernel(
        const float* __restrict__ feat, const unsigned int* __restrict__ bins,
        const int* __restrict__ gcur, int* __restrict__ ovf_cnt,
        int* __restrict__ ovf, int* __restrict__ deg_io,
        float* __restrict__ out, int n_nodes, int cap_seg) {
    __shared__ int sq[NPP * QCAP];   // 16*128*4 = 8 KB
    __shared__ int scnt[NPP];
    int tid = threadIdx.x;
    int p = blockIdx.x;
    int bstart = p * NPP;
    if (tid < NPP) scnt[tid] = 0;
    __syncthreads();

    int cnt = gcur[p];
    if (cnt > cap_seg) cnt = cap_seg;
    const unsigned int* seg = bins + (size_t)p * cap_seg;
    for (int i = tid; i < cnt; i += blockDim.x) {
        unsigned int pk = seg[i];
        int dl = (int)(pk >> 27);
        int s  = (int)(pk & 0x7FFFFFFu);
        int pos = atomicAdd(&scnt[dl], 1);
        if (pos < QCAP) {
            sq[dl * QCAP + pos] = s;
        } else {
            int o = atomicAdd(ovf_cnt, 1);
            if (o < MAX_OVF) { ovf[2 * o] = s; ovf[2 * o + 1] = bstart + dl; }
        }
    }
    __syncthreads();

    int wave = tid >> 6;
    int lane = tid & 63;
    const float2* f2 = (const float2*)feat;   // 64 float2 per row
    for (int ln = wave; ln < NPP; ln += 4) {
        int node = bstart + ln;
        if (node >= n_nodes) break;
        int full = scnt[ln] + deg_io[node];    // + segment-overflow edges
        int degq = scnt[ln] < QCAP ? scnt[ln] : QCAP;
        const int* q = &sq[ln * QCAP];
        float2 a0 = {0.f, 0.f}, a1 = {0.f, 0.f};
        float2 a2 = {0.f, 0.f}, a3 = {0.f, 0.f};
        int i = 0;
        for (; i + 4 <= degq; i += 4) {
            int4 s4 = *(const int4*)&q[i];     // wave-uniform LDS broadcast
            float2 v0 = f2[(size_t)s4.x * 64 + lane];
            float2 v1 = f2[(size_t)s4.y * 64 + lane];
            float2 v2 = f2[(size_t)s4.z * 64 + lane];
            float2 v3 = f2[(size_t)s4.w * 64 + lane];
            a0.x += v0.x; a0.y += v0.y;
            a1.x += v1.x; a1.y += v1.y;
            a2.x += v2.x; a2.y += v2.y;
            a3.x += v3.x; a3.y += v3.y;
        }
        for (; i < degq; ++i) {
            int s = q[i];
            float2 v = f2[(size_t)s * 64 + lane];
            a0.x += v.x; a0.y += v.y;
        }
        float2 r;
        r.x = (a0.x + a1.x) + (a2.x + a3.x);
        r.y = (a0.y + a1.y) + (a2.y + a3.y);
        float sc = rsqrtf((float)(full > 1 ? full : 1));
        r.x *= sc; r.y *= sc;
        ((float2*)out)[(size_t)node * 64 + lane] = r;
        if (lane == 0) deg_io[node] = full;    // final degree for patch
    }
}

// Overflow edges (expected: none). deg_io holds final degrees.
__global__ void patch_kernel(const float* __restrict__ feat,
                             const int* __restrict__ deg_io,
                             const int* __restrict__ ovf_cnt,
                             const int* __restrict__ ovf,
                             float* __restrict__ out) {
    int novf = *ovf_cnt;
    if (novf > MAX_OVF) novf = MAX_OVF;
    long long total  = (long long)novf * D_FEAT;
    long long stride = (long long)gridDim.x * blockDim.x;
    for (long long i = (long long)blockIdx.x * blockDim.x + threadIdx.x;
         i < total; i += stride) {
        int o = (int)(i >> 7);
        int f = (int)(i & 127);
        int s = ovf[2 * o];
        int d = ovf[2 * o + 1];
        int dgi = deg_io[d]; if (dgi < 1) dgi = 1;
        float v = feat[(long long)s * D_FEAT + f] * rsqrtf((float)dgi);
        atomicAdd(&out[(long long)d * D_FEAT + f], v);
    }
}

// ---------------- fallback path (fp32 atomics) ----------------

__global__ void zero_kernel(float* __restrict__ out, float* __restrict__ deg,
                            int n_out, int n_deg) {
    int i = blockIdx.x * blockDim.x + threadIdx.x;
    if (i < n_out) out[i] = 0.0f;
    if (i < n_deg) deg[i] = 0.0f;
}

__global__ void scatter_kernel(const float* __restrict__ feat,
                               const int* __restrict__ src,
                               const int* __restrict__ dst,
                               float* __restrict__ out,
                               float* __restrict__ deg,
                               int n_edges) {
    long long gid = (long long)blockIdx.x * blockDim.x + threadIdx.x;
    int e = (int)(gid >> 7);
    int f = (int)(gid & 127);
    if (e >= n_edges) return;
    int s = src[e];
    int d = dst[e];
    float v = feat[(long long)s * D_FEAT + f];
    atomicAdd(&out[(long long)d * D_FEAT + f], v);
    if (f == 0) atomicAdd(&deg[d], 1.0f);
}

__global__ void norm_kernel(float* __restrict__ out, const float* __restrict__ deg,
                            int n_out) {
    int gid = blockIdx.x * blockDim.x + threadIdx.x;
    if (gid >= n_out) return;
    int i = gid >> 7;
    float dg = fmaxf(deg[i], 1.0f);
    out[gid] = out[gid] * rsqrtf(dg);
}

extern "C" void kernel_launch(void* const* d_in, const int* in_sizes, int n_in,
                              void* d_out, int out_size, void* d_ws, size_t ws_size,
                              hipStream_t stream) {
    const float* feat = (const float*)d_in[0];
    const int*   src  = (const int*)d_in[1];
    const int*   dst  = (const int*)d_in[2];
    float* out = (float*)d_out;

    const int n_edges = in_sizes[1];
    const int n_out   = out_size;            // n_nodes * 128
    const int n_nodes = n_out / D_FEAT;

    int npart = (n_nodes + NPP - 1) / NPP;
    // segment capacity: mean + 8*sigma + slack, rounded to 16
    int avg = n_edges / (npart > 0 ? npart : 1);
    int cap_seg = avg + 8 * (int)sqrtf((float)(avg > 0 ? avg : 1)) + 64;
    cap_seg = (cap_seg + 15) & ~15;

    // ws layout (ints): gcur[npart] | ovf_cnt[1]+pad[3] | deg[n_nodes]
    //                   | ovf[2*MAX_OVF] | bins[npart*cap_seg]
    size_t zero_ints = (size_t)npart + 4 + n_nodes;
    size_t need = (zero_ints + 2 * MAX_OVF + (size_t)npart * cap_seg) * sizeof(int);

    if (ws_size >= need && npart <= MAX_NPART && n_nodes <= (1 << 27)) {
        int* gcur    = (int*)d_ws;
        int* ovf_cnt = gcur + npart;
        int* deg_io  = ovf_cnt + 4;
        int* ovf     = deg_io + n_nodes;
        unsigned int* bins = (unsigned int*)(ovf + 2 * MAX_OVF);

        {
            int threads = 256;
            int blocks = (int)((zero_ints + threads - 1) / threads);
            zero_ws_kernel<<<blocks, threads, 0, stream>>>((int*)d_ws,
                                                           (int)zero_ints);
        }
        {
            int blocks = (n_edges + EPB - 1) / EPB;
            bin_kernel<<<blocks, 1024, 0, stream>>>(
                src, dst, gcur, ovf_cnt, ovf, deg_io, bins,
                n_edges, npart, cap_seg);
        }
        gather_part_kernel<<<npart, 256, 0, stream>>>(
            feat, bins, gcur, ovf_cnt, ovf, deg_io, out, n_nodes, cap_seg);
        patch_kernel<<<32, 256, 0, stream>>>(feat, deg_io, ovf_cnt, ovf, out);
    } else {
        float* deg = (float*)d_ws;
        {
            int threads = 256;
            int blocks = (n_out + threads - 1) / threads;
            zero_kernel<<<blocks, threads, 0, stream>>>(out, deg, n_out, n_nodes);
        }
        {
            long long total = (long long)n_edges * D_FEAT;
            int threads = 256;
            int blocks = (int)((total + threads - 1) / threads);
            scatter_kernel<<<blocks, threads, 0, stream>>>(feat, src, dst, out, deg, n_edges);
        }
        {
            int threads = 256;
            int blocks = (n_out + threads - 1) / threads;
            norm_kernel<<<blocks, threads, 0, stream>>>(out, deg, n_out);
        }
    }
}

// Round 8
// 47.547 us; speedup vs baseline: 2.1942x; 1.1699x over previous
//
#include <hip/hip_runtime.h>

#define D_FEAT 128
#define NPP 16            // nodes per partition (p = d >> 4)
#define QCAP 128          // per-node LDS queue capacity
#define MAX_NPART 1024    // scan width; supports n_nodes <= 16384
#define MAX_OVF 8192
#define BIN_THREADS 1024
#define EPT 4
#define EPB (BIN_THREADS * EPT)   // 4096 edges per bin block

typedef unsigned int u32;

__device__ __forceinline__ u32 f2bf(float f) {   // RNE fp32 -> bf16
    u32 x = __float_as_uint(f);
    return (x + 0x7FFFu + ((x >> 16) & 1u)) >> 16;
}

// ---------------- Kernel 0: zero control ws + convert feat -> bf16 ----------
__global__ void prep_kernel(const float* __restrict__ feat,
                            int* __restrict__ zp, int zn,
                            u32* __restrict__ fbf, int npacks) {
    int i = blockIdx.x * blockDim.x + threadIdx.x;
    if (i < zn) zp[i] = 0;
    if (i < npacks) {                 // 4 floats -> 2 packed bf16x2
        float4 v = ((const float4*)feat)[i];
        u32 a = f2bf(v.x) | (f2bf(v.y) << 16);
        u32 b = f2bf(v.z) | (f2bf(v.w) << 16);
        ((uint2*)fbf)[i] = make_uint2(a, b);
    }
}

// ---------------- Kernel 1: partitioned binning with LDS multisplit --------
// Per block: rank edges per partition (LDS atomics), reserve global segment
// space once per (block,partition), stage edges partition-sorted in LDS,
// copy out contiguously (coalesced partial-line runs instead of scattered
// per-lane stores). pack = p<<20 | dl<<16 | s  (p<=1023, dl<16, s<16384).
__global__ __launch_bounds__(BIN_THREADS) void bin_kernel(
        const int* __restrict__ src, const int* __restrict__ dst,
        int* __restrict__ gcur, int* __restrict__ ovf_cnt,
        int* __restrict__ ovf, int* __restrict__ ovf_deg,
        u32* __restrict__ bins, int n_edges, int npart, int cap_seg) {
    __shared__ int lcnt[MAX_NPART];
    __shared__ int lbase[MAX_NPART];   // global base per partition
    __shared__ int sscan[MAX_NPART];   // inclusive scan of lcnt
    __shared__ u32 stage[EPB];
    int tid = threadIdx.x;
    lcnt[tid] = 0;
    __syncthreads();

    int base = blockIdx.x * EPB + tid * 4;
    int s0 = 0, s1 = 0, s2 = 0, s3 = 0, d0 = -1, d1 = -1, d2 = -1, d3 = -1;
    if (base + 3 < n_edges) {
        int4 sv = ((const int4*)src)[base >> 2];
        int4 dv = ((const int4*)dst)[base >> 2];
        s0 = sv.x; s1 = sv.y; s2 = sv.z; s3 = sv.w;
        d0 = dv.x; d1 = dv.y; d2 = dv.z; d3 = dv.w;
    } else if (base < n_edges) {
        if (base + 0 < n_edges) { s0 = src[base + 0]; d0 = dst[base + 0]; }
        if (base + 1 < n_edges) { s1 = src[base + 1]; d1 = dst[base + 1]; }
        if (base + 2 < n_edges) { s2 = src[base + 2]; d2 = dst[base + 2]; }
        if (base + 3 < n_edges) { s3 = src[base + 3]; d3 = dst[base + 3]; }
    }
    int p0 = d0 >> 4, p1 = d1 >> 4, p2 = d2 >> 4, p3 = d3 >> 4;
    int r0 = 0, r1 = 0, r2 = 0, r3 = 0;
    if (d0 >= 0) r0 = atomicAdd(&lcnt[p0], 1);
    if (d1 >= 0) r1 = atomicAdd(&lcnt[p1], 1);
    if (d2 >= 0) r2 = atomicAdd(&lcnt[p2], 1);
    if (d3 >= 0) r3 = atomicAdd(&lcnt[p3], 1);
    __syncthreads();

    int myc = lcnt[tid];
    if (tid < npart && myc > 0) lbase[tid] = atomicAdd(&gcur[tid], myc);
    sscan[tid] = myc;
    __syncthreads();
    // Hillis-Steele inclusive scan over MAX_NPART slots
    for (int off = 1; off < MAX_NPART; off <<= 1) {
        int v = 0;
        if (tid >= off) v = sscan[tid - off];
        __syncthreads();
        sscan[tid] += v;
        __syncthreads();
    }

    // stage edges partition-sorted: slot = exclusive_base(p) + rank
    #define STAGE(dK, sK, pK, rK)                                             \
        if (dK >= 0) {                                                        \
            int ex = sscan[pK] - lcnt[pK];                                    \
            stage[ex + rK] = ((u32)pK << 20) |                                \
                             ((u32)(dK & (NPP - 1)) << 16) | (u32)sK;         \
        }
    STAGE(d0, s0, p0, r0)
    STAGE(d1, s1, p1, r1)
    STAGE(d2, s2, p2, r2)
    STAGE(d3, s3, p3, r3)
    #undef STAGE
    __syncthreads();

    int total = sscan[MAX_NPART - 1];
    for (int i = tid; i < total; i += BIN_THREADS) {
        u32 pk = stage[i];
        int p = (int)(pk >> 20);
        int ex = sscan[p] - lcnt[p];
        int idx = lbase[p] + (i - ex);
        if (idx < cap_seg) {
            bins[(size_t)p * cap_seg + idx] = pk & 0xFFFFFu;
        } else {
            int s = (int)(pk & 0xFFFFu);
            int d = p * NPP + (int)((pk >> 16) & (NPP - 1));
            int o = atomicAdd(ovf_cnt, 1);
            if (o < MAX_OVF) { ovf[2 * o] = s; ovf[2 * o + 1] = d; }
            atomicAdd(&ovf_deg[d], 1);
        }
    }
}

// ---------------- Kernel 2: per-partition queue build + bf16 gather --------
__global__ __launch_bounds__(256) void gather_part_kernel(
        const u32* __restrict__ fbf, const u32* __restrict__ bins,
        const int* __restrict__ gcur, int* __restrict__ ovf_cnt,
        int* __restrict__ ovf, int* __restrict__ deg_io,
        float* __restrict__ out, int n_nodes, int cap_seg) {
    __shared__ int sq[NPP * QCAP];   // 8 KB
    __shared__ int scnt[NPP];
    int tid = threadIdx.x;
    int p = blockIdx.x;
    int bstart = p * NPP;
    if (tid < NPP) scnt[tid] = 0;
    __syncthreads();

    int cnt = gcur[p];
    if (cnt > cap_seg) cnt = cap_seg;
    const u32* seg = bins + (size_t)p * cap_seg;
    for (int i = tid; i < cnt; i += blockDim.x) {
        u32 pk = seg[i];
        int dl = (int)((pk >> 16) & (NPP - 1));
        int s  = (int)(pk & 0xFFFFu);
        int pos = atomicAdd(&scnt[dl], 1);
        if (pos < QCAP) {
            sq[dl * QCAP + pos] = s;
        } else {
            int o = atomicAdd(ovf_cnt, 1);
            if (o < MAX_OVF) { ovf[2 * o] = s; ovf[2 * o + 1] = bstart + dl; }
        }
    }
    __syncthreads();

    int wave = tid >> 6;
    int lane = tid & 63;
    for (int ln = wave; ln < NPP; ln += 4) {
        int node = bstart + ln;
        if (node >= n_nodes) break;
        int full = scnt[ln] + deg_io[node];   // + bin-segment overflow edges
        int degq = scnt[ln] < QCAP ? scnt[ln] : QCAP;
        const int* q = &sq[ln * QCAP];
        float ax0 = 0.f, ay0 = 0.f, ax1 = 0.f, ay1 = 0.f;
        float ax2 = 0.f, ay2 = 0.f, ax3 = 0.f, ay3 = 0.f;
        int i = 0;
        for (; i + 4 <= degq; i += 4) {
            int4 s4 = *(const int4*)&q[i];     // wave-uniform LDS broadcast
            u32 u0 = fbf[(size_t)s4.x * 64 + lane];   // 2 bf16 cols per lane
            u32 u1 = fbf[(size_t)s4.y * 64 + lane];
            u32 u2 = fbf[(size_t)s4.z * 64 + lane];
            u32 u3 = fbf[(size_t)s4.w * 64 + lane];
            ax0 += __uint_as_float(u0 << 16); ay0 += __uint_as_float(u0 & 0xFFFF0000u);
            ax1 += __uint_as_float(u1 << 16); ay1 += __uint_as_float(u1 & 0xFFFF0000u);
            ax2 += __uint_as_float(u2 << 16); ay2 += __uint_as_float(u2 & 0xFFFF0000u);
            ax3 += __uint_as_float(u3 << 16); ay3 += __uint_as_float(u3 & 0xFFFF0000u);
        }
        for (; i < degq; ++i) {
            u32 u = fbf[(size_t)q[i] * 64 + lane];
            ax0 += __uint_as_float(u << 16);
            ay0 += __uint_as_float(u & 0xFFFF0000u);
        }
        float2 r;
        r.x = (ax0 + ax1) + (ax2 + ax3);
        r.y = (ay0 + ay1) + (ay2 + ay3);
        float sc = rsqrtf((float)(full > 1 ? full : 1));
        r.x *= sc; r.y *= sc;
        ((float2*)out)[(size_t)node * 64 + lane] = r;    // cols (2l, 2l+1)
        if (lane == 0) deg_io[node] = full;              // final degree
    }
}

// Overflow edges (expected: none). Uses full-precision feat.
__global__ void patch_kernel(const float* __restrict__ feat,
                             const int* __restrict__ deg_io,
                             const int* __restrict__ ovf_cnt,
                             const int* __restrict__ ovf,
                             float* __restrict__ out) {
    int novf = *ovf_cnt;
    if (novf > MAX_OVF) novf = MAX_OVF;
    long long total  = (long long)novf * D_FEAT;
    long long stride = (long long)gridDim.x * blockDim.x;
    for (long long i = (long long)blockIdx.x * blockDim.x + threadIdx.x;
         i < total; i += stride) {
        int o = (int)(i >> 7);
        int f = (int)(i & 127);
        int s = ovf[2 * o];
        int d = ovf[2 * o + 1];
        int dgi = deg_io[d]; if (dgi < 1) dgi = 1;
        float v = feat[(long long)s * D_FEAT + f] * rsqrtf((float)dgi);
        atomicAdd(&out[(long long)d * D_FEAT + f], v);
    }
}

// ---------------- fallback path (fp32 atomics) ----------------

__global__ void zero_kernel(float* __restrict__ out, float* __restrict__ deg,
                            int n_out, int n_deg) {
    int i = blockIdx.x * blockDim.x + threadIdx.x;
    if (i < n_out) out[i] = 0.0f;
    if (i < n_deg) deg[i] = 0.0f;
}

__global__ void scatter_kernel(const float* __restrict__ feat,
                               const int* __restrict__ src,
                               const int* __restrict__ dst,
                               float* __restrict__ out,
                               float* __restrict__ deg,
                               int n_edges) {
    long long gid = (long long)blockIdx.x * blockDim.x + threadIdx.x;
    int e = (int)(gid >> 7);
    int f = (int)(gid & 127);
    if (e >= n_edges) return;
    int s = src[e];
    int d = dst[e];
    float v = feat[(long long)s * D_FEAT + f];
    atomicAdd(&out[(long long)d * D_FEAT + f], v);
    if (f == 0) atomicAdd(&deg[d], 1.0f);
}

__global__ void norm_kernel(float* __restrict__ out, const float* __restrict__ deg,
                            int n_out) {
    int gid = blockIdx.x * blockDim.x + threadIdx.x;
    if (gid >= n_out) return;
    int i = gid >> 7;
    float dg = fmaxf(deg[i], 1.0f);
    out[gid] = out[gid] * rsqrtf(dg);
}

extern "C" void kernel_launch(void* const* d_in, const int* in_sizes, int n_in,
                              void* d_out, int out_size, void* d_ws, size_t ws_size,
                              hipStream_t stream) {
    const float* feat = (const float*)d_in[0];
    const int*   src  = (const int*)d_in[1];
    const int*   dst  = (const int*)d_in[2];
    float* out = (float*)d_out;

    const int n_edges = in_sizes[1];
    const int n_out   = out_size;            // n_nodes * 128
    const int n_nodes = n_out / D_FEAT;

    int npart = (n_nodes + NPP - 1) / NPP;
    int avg = n_edges / (npart > 0 ? npart : 1);
    int cap_seg = avg + 8 * (int)sqrtf((float)(avg > 0 ? avg : 1)) + 64;
    cap_seg = (cap_seg + 15) & ~15;

    // ws (ints): gcur[npart] | ovf_cnt[1]+pad[3] | deg[n_nodes] | ovf[2*MAX_OVF]
    //            | bins[npart*cap_seg] | fbf[n_out/2 u32]
    size_t zero_ints = (size_t)npart + 4 + n_nodes;
    size_t need = (zero_ints + 2 * MAX_OVF + (size_t)npart * cap_seg
                   + (size_t)n_out / 2) * sizeof(int);

    if (ws_size >= need && npart <= MAX_NPART && n_nodes <= 16384) {
        int* gcur    = (int*)d_ws;
        int* ovf_cnt = gcur + npart;
        int* deg_io  = ovf_cnt + 4;
        int* ovf     = deg_io + n_nodes;
        u32* bins    = (u32*)(ovf + 2 * MAX_OVF);
        u32* fbf     = bins + (size_t)npart * cap_seg;

        {
            int npacks = n_out / 4;
            int work = npacks > (int)zero_ints ? npacks : (int)zero_ints;
            int threads = 256;
            int blocks = (work + threads - 1) / threads;
            prep_kernel<<<blocks, threads, 0, stream>>>(feat, (int*)d_ws,
                                                        (int)zero_ints, fbf,
                                                        npacks);
        }
        {
            int blocks = (n_edges + EPB - 1) / EPB;
            bin_kernel<<<blocks, BIN_THREADS, 0, stream>>>(
                src, dst, gcur, ovf_cnt, ovf, deg_io, bins,
                n_edges, npart, cap_seg);
        }
        gather_part_kernel<<<npart, 256, 0, stream>>>(
            fbf, bins, gcur, ovf_cnt, ovf, deg_io, out, n_nodes, cap_seg);
        patch_kernel<<<32, 256, 0, stream>>>(feat, deg_io, ovf_cnt, ovf, out);
    } else {
        float* deg = (float*)d_ws;
        {
            int threads = 256;
            int blocks = (n_out + threads - 1) / threads;
            zero_kernel<<<blocks, threads, 0, stream>>>(out, deg, n_out, n_nodes);
        }
        {
            long long total = (long long)n_edges * D_FEAT;
            int threads = 256;
            int blocks = (int)((total + threads - 1) / threads);
            scatter_kernel<<<blocks, threads, 0, stream>>>(feat, src, dst, out, deg, n_edges);
        }
        {
            int threads = 256;
            int blocks = (n_out + threads - 1) / threads;
            norm_kernel<<<blocks, threads, 0, stream>>>(out, deg, n_out);
        }
    }
}

// Round 9
// 45.695 us; speedup vs baseline: 2.2831x; 1.0405x over previous
//
#include <hip/hip_runtime.h>

#define D_FEAT 128
#define NPP 16            // nodes per partition (p = d >> 4)
#define QCAP 128          // per-node LDS queue capacity (max deg ~115 expected)
#define PCAP 16           // per-(block,partition) staging capacity (lambda=3.3)
#define MAX_NPART 640     // supports n_nodes <= 10240
#define MAX_OVF 8192
#define LOCAL_OVF 64
#define BIN_THREADS 512
#define EPT 4
#define EPB (BIN_THREADS * EPT)   // 2048 edges per bin block

typedef unsigned int u32;

__device__ __forceinline__ u32 f2bf(float f) {   // RNE fp32 -> bf16
    u32 x = __float_as_uint(f);
    return (x + 0x7FFFu + ((x >> 16) & 1u)) >> 16;
}
__device__ __forceinline__ float bf_lo(u32 u) { return __uint_as_float(u << 16); }
__device__ __forceinline__ float bf_hi(u32 u) { return __uint_as_float(u & 0xFFFF0000u); }

// ---------------- Kernel 0: zero control ws + convert feat -> bf16 ----------
__global__ void prep_kernel(const float* __restrict__ feat,
                            int* __restrict__ zp, int zn,
                            u32* __restrict__ fbf, int npacks) {
    int i = blockIdx.x * blockDim.x + threadIdx.x;
    if (i < zn) zp[i] = 0;
    if (i < npacks) {                 // 4 floats -> uint2 of 4 bf16
        float4 v = ((const float4*)feat)[i];
        u32 a = f2bf(v.x) | (f2bf(v.y) << 16);
        u32 b = f2bf(v.z) | (f2bf(v.w) << 16);
        ((uint2*)fbf)[i] = make_uint2(a, b);
    }
}

// ---------------- Kernel 1: binning, scan-free fixed-capacity multisplit ----
// Block: 2048 edges. Rank per partition via LDS atomics, stage at p*PCAP+rank
// (PCAP=16, lambda=3.3 -> overflow ~0, exact via global ovf list), reserve
// global segment space once per (block,partition), 32-lane-group sweep copy.
__global__ __launch_bounds__(BIN_THREADS) void bin_kernel(
        const int* __restrict__ src, const int* __restrict__ dst,
        int* __restrict__ gcur, int* __restrict__ ovf_cnt,
        int* __restrict__ ovf, u32* __restrict__ bins,
        int n_edges, int npart, int cap_seg) {
    __shared__ int lcnt[MAX_NPART];
    __shared__ int lbase[MAX_NPART];
    __shared__ u32 stage[MAX_NPART * PCAP];   // 40 KB
    int tid = threadIdx.x;
    for (int i = tid; i < npart; i += BIN_THREADS) lcnt[i] = 0;
    __syncthreads();

    int base = blockIdx.x * EPB + tid * 4;
    int s0 = 0, s1 = 0, s2 = 0, s3 = 0, d0 = -1, d1 = -1, d2 = -1, d3 = -1;
    if (base + 3 < n_edges) {
        int4 sv = ((const int4*)src)[base >> 2];
        int4 dv = ((const int4*)dst)[base >> 2];
        s0 = sv.x; s1 = sv.y; s2 = sv.z; s3 = sv.w;
        d0 = dv.x; d1 = dv.y; d2 = dv.z; d3 = dv.w;
    } else if (base < n_edges) {
        if (base + 0 < n_edges) { s0 = src[base + 0]; d0 = dst[base + 0]; }
        if (base + 1 < n_edges) { s1 = src[base + 1]; d1 = dst[base + 1]; }
        if (base + 2 < n_edges) { s2 = src[base + 2]; d2 = dst[base + 2]; }
        if (base + 3 < n_edges) { s3 = src[base + 3]; d3 = dst[base + 3]; }
    }
    #define RANK(dK, sK)                                                      \
        if (dK >= 0) {                                                        \
            int pK = dK >> 4;                                                 \
            int r = atomicAdd(&lcnt[pK], 1);                                  \
            if (r < PCAP) {                                                   \
                stage[pK * PCAP + r] =                                        \
                    ((u32)(dK & (NPP - 1)) << 16) | (u32)sK;                  \
            } else {                                                          \
                int o = atomicAdd(ovf_cnt, 1);                                \
                if (o < MAX_OVF) { ovf[2 * o] = sK; ovf[2 * o + 1] = dK; }    \
            }                                                                 \
        }
    RANK(d0, s0)
    RANK(d1, s1)
    RANK(d2, s2)
    RANK(d3, s3)
    #undef RANK
    __syncthreads();

    for (int i = tid; i < npart; i += BIN_THREADS) {
        int c = lcnt[i];
        if (c > PCAP) c = PCAP;
        lcnt[i] = c;
        if (c > 0) lbase[i] = atomicAdd(&gcur[i], c);
    }
    __syncthreads();

    int grp = tid >> 5, nl = tid & 31;
    for (int p = grp; p < npart; p += (BIN_THREADS / 32)) {
        int c = lcnt[p];
        if (nl < c) {
            int idx = lbase[p] + nl;
            u32 pk = stage[p * PCAP + nl];
            if (idx < cap_seg) {
                bins[(size_t)p * cap_seg + idx] = pk;
            } else {
                int s = (int)(pk & 0xFFFFu);
                int d = p * NPP + (int)(pk >> 16);
                int o = atomicAdd(ovf_cnt, 1);
                if (o < MAX_OVF) { ovf[2 * o] = s; ovf[2 * o + 1] = d; }
            }
        }
    }
}

// ---------------- Kernel 2: queue build + bf16 gather + folded patch --------
// Half-wave (32 lanes) per node, uint2 (4 bf16 cols) per lane. Overflow
// (bin-segment + local queue) handled exactly in-block after main writes.
__global__ __launch_bounds__(256) void gather_kernel(
        const u32* __restrict__ fbf, const u32* __restrict__ bins,
        const int* __restrict__ gcur, const int* __restrict__ ovf_cnt,
        const int* __restrict__ ovf, float* __restrict__ out,
        int n_nodes, int cap_seg) {
    __shared__ __attribute__((aligned(16))) int sq[NPP * QCAP];   // 8 KB
    __shared__ int scnt[NPP];
    __shared__ int sovf_deg[NPP];
    __shared__ int lovf[LOCAL_OVF];
    __shared__ int lovf_cnt;
    __shared__ int snovf;
    int tid = threadIdx.x;
    int p = blockIdx.x;
    int bstart = p * NPP;
    if (tid < NPP) { scnt[tid] = 0; sovf_deg[tid] = 0; }
    if (tid == 0) {
        lovf_cnt = 0;
        int nv = *ovf_cnt;
        snovf = nv > MAX_OVF ? MAX_OVF : nv;
    }
    __syncthreads();

    int cnt = gcur[p];
    if (cnt > cap_seg) cnt = cap_seg;
    const u32* seg = bins + (size_t)p * cap_seg;
    for (int i = tid; i < cnt; i += 256) {
        u32 pk = seg[i];
        int dl = (int)(pk >> 16);
        int s  = (int)(pk & 0xFFFFu);
        int pos = atomicAdd(&scnt[dl], 1);
        if (pos < QCAP) {
            sq[dl * QCAP + pos] = s;
        } else {
            int o = atomicAdd(&lovf_cnt, 1);
            if (o < LOCAL_OVF) lovf[o] = (dl << 16) | s;
        }
    }
    __syncthreads();
    int novf = snovf;
    if (novf > 0) {
        for (int i = tid; i < novf; i += 256) {
            int d = ovf[2 * i + 1];
            if (d >= bstart && d < bstart + NPP && d < n_nodes)
                atomicAdd(&sovf_deg[d - bstart], 1);
        }
        __syncthreads();
    }

    int hw = tid >> 5;        // half-wave id 0..7
    int hl = tid & 31;        // lane in half
    const uint2* f2 = (const uint2*)fbf;   // row = 32 uint2 (128 bf16)
    for (int ln = hw; ln < NPP; ln += 8) {
        int node = bstart + ln;
        if (node < n_nodes) {
            int full = scnt[ln] + sovf_deg[ln];
            int degq = scnt[ln] < QCAP ? scnt[ln] : QCAP;
            const int* q = &sq[ln * QCAP];
            float a0 = 0.f, a1 = 0.f, a2 = 0.f, a3 = 0.f;
            float b0 = 0.f, b1 = 0.f, b2 = 0.f, b3 = 0.f;
            int i = 0;
            for (; i + 4 <= degq; i += 4) {
                int4 s4 = *(const int4*)&q[i];   // uniform per half -> broadcast
                uint2 u0 = f2[(size_t)s4.x * 32 + hl];
                uint2 u1 = f2[(size_t)s4.y * 32 + hl];
                uint2 u2 = f2[(size_t)s4.z * 32 + hl];
                uint2 u3 = f2[(size_t)s4.w * 32 + hl];
                a0 += bf_lo(u0.x); a1 += bf_hi(u0.x); a2 += bf_lo(u0.y); a3 += bf_hi(u0.y);
                b0 += bf_lo(u1.x); b1 += bf_hi(u1.x); b2 += bf_lo(u1.y); b3 += bf_hi(u1.y);
                a0 += bf_lo(u2.x); a1 += bf_hi(u2.x); a2 += bf_lo(u2.y); a3 += bf_hi(u2.y);
                b0 += bf_lo(u3.x); b1 += bf_hi(u3.x); b2 += bf_lo(u3.y); b3 += bf_hi(u3.y);
            }
            for (; i < degq; ++i) {
                uint2 u = f2[(size_t)q[i] * 32 + hl];
                a0 += bf_lo(u.x); a1 += bf_hi(u.x);
                a2 += bf_lo(u.y); a3 += bf_hi(u.y);
            }
            float sc = rsqrtf((float)(full > 1 ? full : 1));
            float4 r;
            r.x = (a0 + b0) * sc;
            r.y = (a1 + b1) * sc;
            r.z = (a2 + b2) * sc;
            r.w = (a3 + b3) * sc;
            ((float4*)out)[(size_t)node * 32 + hl] = r;   // cols 4hl..4hl+3
        }
    }
    __syncthreads();

    // local queue overflow (expected 0)
    int lc = lovf_cnt; if (lc > LOCAL_OVF) lc = LOCAL_OVF;
    for (int k = hw; k < lc; k += 8) {
        int ent = lovf[k];
        int dl = ent >> 16;
        int s  = ent & 0xFFFF;
        int full = scnt[dl] + sovf_deg[dl];
        float sc = rsqrtf((float)(full > 1 ? full : 1));
        uint2 u = f2[(size_t)s * 32 + hl];
        float* orow = out + (size_t)(bstart + dl) * D_FEAT + hl * 4;
        atomicAdd(&orow[0], bf_lo(u.x) * sc);
        atomicAdd(&orow[1], bf_hi(u.x) * sc);
        atomicAdd(&orow[2], bf_lo(u.y) * sc);
        atomicAdd(&orow[3], bf_hi(u.y) * sc);
    }
    // bin-segment overflow edges landing in my partition (expected 0)
    if (novf > 0) {
        for (int k = hw; k < novf; k += 8) {
            int d = ovf[2 * k + 1];
            if (d >= bstart && d < bstart + NPP && d < n_nodes) {
                int s  = ovf[2 * k];
                int dl = d - bstart;
                int full = scnt[dl] + sovf_deg[dl];
                float sc = rsqrtf((float)(full > 1 ? full : 1));
                uint2 u = f2[(size_t)s * 32 + hl];
                float* orow = out + (size_t)d * D_FEAT + hl * 4;
                atomicAdd(&orow[0], bf_lo(u.x) * sc);
                atomicAdd(&orow[1], bf_hi(u.x) * sc);
                atomicAdd(&orow[2], bf_lo(u.y) * sc);
                atomicAdd(&orow[3], bf_hi(u.y) * sc);
            }
        }
    }
}

// ---------------- fallback path (fp32 atomics) ----------------

__global__ void zero_kernel(float* __restrict__ out, float* __restrict__ deg,
                            int n_out, int n_deg) {
    int i = blockIdx.x * blockDim.x + threadIdx.x;
    if (i < n_out) out[i] = 0.0f;
    if (i < n_deg) deg[i] = 0.0f;
}

__global__ void scatter_kernel(const float* __restrict__ feat,
                               const int* __restrict__ src,
                               const int* __restrict__ dst,
                               float* __restrict__ out,
                               float* __restrict__ deg,
                               int n_edges) {
    long long gid = (long long)blockIdx.x * blockDim.x + threadIdx.x;
    int e = (int)(gid >> 7);
    int f = (int)(gid & 127);
    if (e >= n_edges) return;
    int s = src[e];
    int d = dst[e];
    float v = feat[(long long)s * D_FEAT + f];
    atomicAdd(&out[(long long)d * D_FEAT + f], v);
    if (f == 0) atomicAdd(&deg[d], 1.0f);
}

__global__ void norm_kernel(float* __restrict__ out, const float* __restrict__ deg,
                            int n_out) {
    int gid = blockIdx.x * blockDim.x + threadIdx.x;
    if (gid >= n_out) return;
    int i = gid >> 7;
    float dg = fmaxf(deg[i], 1.0f);
    out[gid] = out[gid] * rsqrtf(dg);
}

extern "C" void kernel_launch(void* const* d_in, const int* in_sizes, int n_in,
                              void* d_out, int out_size, void* d_ws, size_t ws_size,
                              hipStream_t stream) {
    const float* feat = (const float*)d_in[0];
    const int*   src  = (const int*)d_in[1];
    const int*   dst  = (const int*)d_in[2];
    float* out = (float*)d_out;

    const int n_edges = in_sizes[1];
    const int n_out   = out_size;            // n_nodes * 128
    const int n_nodes = n_out / D_FEAT;

    int npart = (n_nodes + NPP - 1) / NPP;
    int avg = n_edges / (npart > 0 ? npart : 1);
    int cap_seg = avg + 8 * (int)sqrtf((float)(avg > 0 ? avg : 1)) + 64;
    cap_seg = (cap_seg + 15) & ~15;

    // ws (ints): gcur[npart] | ovf_cnt[1]+pad[3] | ovf[2*MAX_OVF]
    //            | bins[npart*cap_seg] | fbf[n_out/2 u32]
    size_t zero_ints = (size_t)npart + 4;
    size_t need = (zero_ints + 2 * MAX_OVF + (size_t)npart * cap_seg
                   + (size_t)n_out / 2) * sizeof(int);

    if (ws_size >= need && npart <= MAX_NPART) {
        int* gcur    = (int*)d_ws;
        int* ovf_cnt = gcur + npart;
        int* ovf     = ovf_cnt + 4;
        u32* bins    = (u32*)(ovf + 2 * MAX_OVF);
        u32* fbf     = bins + (size_t)npart * cap_seg;

        {
            int npacks = n_out / 4;
            int work = npacks > (int)zero_ints ? npacks : (int)zero_ints;
            int threads = 256;
            int blocks = (work + threads - 1) / threads;
            prep_kernel<<<blocks, threads, 0, stream>>>(feat, (int*)d_ws,
                                                        (int)zero_ints, fbf,
                                                        npacks);
        }
        {
            int blocks = (n_edges + EPB - 1) / EPB;
            bin_kernel<<<blocks, BIN_THREADS, 0, stream>>>(
                src, dst, gcur, ovf_cnt, ovf, bins, n_edges, npart, cap_seg);
        }
        gather_kernel<<<npart, 256, 0, stream>>>(
            fbf, bins, gcur, ovf_cnt, ovf, out, n_nodes, cap_seg);
    } else {
        float* deg = (float*)d_ws;
        {
            int threads = 256;
            int blocks = (n_out + threads - 1) / threads;
            zero_kernel<<<blocks, threads, 0, stream>>>(out, deg, n_out, n_nodes);
        }
        {
            long long total = (long long)n_edges * D_FEAT;
            int threads = 256;
            int blocks = (int)((total + threads - 1) / threads);
            scatter_kernel<<<blocks, threads, 0, stream>>>(feat, src, dst, out, deg, n_edges);
        }
        {
            int threads = 256;
            int blocks = (n_out + threads - 1) / threads;
            norm_kernel<<<blocks, threads, 0, stream>>>(out, deg, n_out);
        }
    }
}

// Round 10
// 37.966 us; speedup vs baseline: 2.7479x; 1.2036x over previous
//
#include <hip/hip_runtime.h>

#define D_FEAT 128
#define NPP 16            // nodes per partition (p = d >> 4)
#define QCAP 128          // per-node LDS queue capacity (max expected deg ~115)
#define PCAP 16           // per-(block,partition) cell capacity (lambda=3.3)
#define MAX_NPART 640     // supports n_nodes <= 10240
#define MAX_OVF 8192
#define LOCAL_OVF 64
#define BIN_THREADS 512
#define EPB (BIN_THREADS * 4)     // 2048 edges per bin block

typedef unsigned int u32;

__device__ __forceinline__ u32 f2bf(float f) {   // RNE fp32 -> bf16
    u32 x = __float_as_uint(f);
    return (x + 0x7FFFu + ((x >> 16) & 1u)) >> 16;
}
__device__ __forceinline__ float bf_lo(u32 u) { return __uint_as_float(u << 16); }
__device__ __forceinline__ float bf_hi(u32 u) { return __uint_as_float(u & 0xFFFF0000u); }

// ---------------- Kernel 1: feat->bf16 + cursor-free binning ----------------
// Deterministic layout: cell (p, q=blockIdx) holds <=PCAP edges at fixed
// offset ((p*nblk+q)*PCAP); counts gcnt[q*npart+p] written coalesced. No
// global cursor atomics, no count zero-init. Cell overflow -> global ovf
// list (expected count 0, exact handling in gather).
__global__ __launch_bounds__(BIN_THREADS) void bin_kernel(
        const int* __restrict__ src, const int* __restrict__ dst,
        const float* __restrict__ feat, u32* __restrict__ fbf,
        int* __restrict__ gcnt, int* __restrict__ ovf_cnt,
        int* __restrict__ ovf, u32* __restrict__ bins,
        int n_edges, int npart, int nblk, int npacks) {
    __shared__ int lcnt[MAX_NPART];
    __shared__ u32 stage[MAX_NPART * PCAP];   // 40 KB
    int tid = threadIdx.x;
    int q = blockIdx.x;

    // fused feat -> packed bf16 (grid-stride)
    for (int i = q * BIN_THREADS + tid; i < npacks;
         i += gridDim.x * BIN_THREADS) {
        float4 v = ((const float4*)feat)[i];
        u32 a = f2bf(v.x) | (f2bf(v.y) << 16);
        u32 b = f2bf(v.z) | (f2bf(v.w) << 16);
        ((uint2*)fbf)[i] = make_uint2(a, b);
    }

    for (int i = tid; i < npart; i += BIN_THREADS) lcnt[i] = 0;
    __syncthreads();

    int base = q * EPB + tid * 4;
    int s0 = 0, s1 = 0, s2 = 0, s3 = 0, d0 = -1, d1 = -1, d2 = -1, d3 = -1;
    if (base + 3 < n_edges) {
        int4 sv = ((const int4*)src)[base >> 2];
        int4 dv = ((const int4*)dst)[base >> 2];
        s0 = sv.x; s1 = sv.y; s2 = sv.z; s3 = sv.w;
        d0 = dv.x; d1 = dv.y; d2 = dv.z; d3 = dv.w;
    } else if (base < n_edges) {
        if (base + 0 < n_edges) { s0 = src[base + 0]; d0 = dst[base + 0]; }
        if (base + 1 < n_edges) { s1 = src[base + 1]; d1 = dst[base + 1]; }
        if (base + 2 < n_edges) { s2 = src[base + 2]; d2 = dst[base + 2]; }
    }
    #define RANK(dK, sK)                                                      \
        if (dK >= 0) {                                                        \
            int pK = dK >> 4;                                                 \
            int r = atomicAdd(&lcnt[pK], 1);                                  \
            if (r < PCAP) {                                                   \
                stage[pK * PCAP + r] =                                        \
                    ((u32)(dK & (NPP - 1)) << 16) | (u32)sK;                  \
            } else {                                                          \
                int o = atomicAdd(ovf_cnt, 1);                                \
                if (o < MAX_OVF) { ovf[2 * o] = sK; ovf[2 * o + 1] = dK; }    \
            }                                                                 \
        }
    RANK(d0, s0)
    RANK(d1, s1)
    RANK(d2, s2)
    RANK(d3, s3)
    #undef RANK
    __syncthreads();

    // 16-lane-group sweep: cell write is one <=64B contiguous run
    int grp = tid >> 4, gl = tid & 15;
    for (int p = grp; p < npart; p += (BIN_THREADS / 16)) {
        int c = lcnt[p]; if (c > PCAP) c = PCAP;
        if (gl < c)
            bins[((size_t)p * nblk + q) * PCAP + gl] = stage[p * PCAP + gl];
    }
    // counts: coalesced row write
    for (int i = tid; i < npart; i += BIN_THREADS) {
        int c = lcnt[i]; if (c > PCAP) c = PCAP;
        gcnt[(size_t)q * npart + i] = c;
    }
}

// ---------------- Kernel 2: queue build + bf16 gather + folded patch --------
// 16-lane group per node, uint4 (8 bf16 cols) per lane. Overflow handled
// exactly in-block after the main writes (expected 0 executions).
__global__ __launch_bounds__(256) void gather_kernel(
        const u32* __restrict__ fbf, const u32* __restrict__ bins,
        const int* __restrict__ gcnt, const int* __restrict__ ovf_cnt,
        const int* __restrict__ ovf, float* __restrict__ out,
        int n_nodes, int npart, int nblk) {
    __shared__ __attribute__((aligned(16))) int sq[NPP * QCAP];   // 8 KB
    __shared__ int scnt[NPP];
    __shared__ int sovf_deg[NPP];
    __shared__ int lovf[LOCAL_OVF];
    __shared__ int lovf_cnt;
    __shared__ int snovf;
    int tid = threadIdx.x;
    int p = blockIdx.x;
    int bstart = p * NPP;
    if (tid < NPP) { scnt[tid] = 0; sovf_deg[tid] = 0; }
    if (tid == 0) {
        lovf_cnt = 0;
        int nv = *ovf_cnt;
        snovf = nv > MAX_OVF ? MAX_OVF : (nv < 0 ? 0 : nv);
    }
    __syncthreads();

    // build per-node queues from this partition's cells
    for (int q = tid; q < nblk; q += 256) {
        int c = gcnt[(size_t)q * npart + p];
        const u32* cell = &bins[((size_t)p * nblk + q) * PCAP];
        for (int r = 0; r < c; ++r) {
            u32 pk = cell[r];
            int dl = (int)(pk >> 16);
            int s  = (int)(pk & 0xFFFFu);
            int pos = atomicAdd(&scnt[dl], 1);
            if (pos < QCAP) {
                sq[dl * QCAP + pos] = s;
            } else {
                int o = atomicAdd(&lovf_cnt, 1);
                if (o < LOCAL_OVF) lovf[o] = (dl << 16) | s;
            }
        }
    }
    __syncthreads();
    int novf = snovf;
    if (novf > 0) {
        for (int i = tid; i < novf; i += 256) {
            int d = ovf[2 * i + 1];
            if (d >= bstart && d < bstart + NPP && d < n_nodes)
                atomicAdd(&sovf_deg[d - bstart], 1);
        }
        __syncthreads();
    }

    int g  = tid >> 4;        // 16 groups, one node each
    int gl = tid & 15;
    const uint4* f4 = (const uint4*)fbf;   // row = 16 uint4 (128 bf16)
    int node = bstart + g;
    if (node < n_nodes) {
        int full = scnt[g] + sovf_deg[g];
        int degq = scnt[g] < QCAP ? scnt[g] : QCAP;
        const int* qq = &sq[g * QCAP];
        float a0 = 0.f, a1 = 0.f, a2 = 0.f, a3 = 0.f;
        float a4 = 0.f, a5 = 0.f, a6 = 0.f, a7 = 0.f;
        int i = 0;
        for (; i + 4 <= degq; i += 4) {
            int4 s4 = *(const int4*)&qq[i];   // uniform per group -> broadcast
            uint4 u0 = f4[(size_t)s4.x * 16 + gl];
            uint4 u1 = f4[(size_t)s4.y * 16 + gl];
            uint4 u2 = f4[(size_t)s4.z * 16 + gl];
            uint4 u3 = f4[(size_t)s4.w * 16 + gl];
            a0 += bf_lo(u0.x); a1 += bf_hi(u0.x); a2 += bf_lo(u0.y); a3 += bf_hi(u0.y);
            a4 += bf_lo(u0.z); a5 += bf_hi(u0.z); a6 += bf_lo(u0.w); a7 += bf_hi(u0.w);
            a0 += bf_lo(u1.x); a1 += bf_hi(u1.x); a2 += bf_lo(u1.y); a3 += bf_hi(u1.y);
            a4 += bf_lo(u1.z); a5 += bf_hi(u1.z); a6 += bf_lo(u1.w); a7 += bf_hi(u1.w);
            a0 += bf_lo(u2.x); a1 += bf_hi(u2.x); a2 += bf_lo(u2.y); a3 += bf_hi(u2.y);
            a4 += bf_lo(u2.z); a5 += bf_hi(u2.z); a6 += bf_lo(u2.w); a7 += bf_hi(u2.w);
            a0 += bf_lo(u3.x); a1 += bf_hi(u3.x); a2 += bf_lo(u3.y); a3 += bf_hi(u3.y);
            a4 += bf_lo(u3.z); a5 += bf_hi(u3.z); a6 += bf_lo(u3.w); a7 += bf_hi(u3.w);
        }
        for (; i < degq; ++i) {
            uint4 u = f4[(size_t)qq[i] * 16 + gl];
            a0 += bf_lo(u.x); a1 += bf_hi(u.x); a2 += bf_lo(u.y); a3 += bf_hi(u.y);
            a4 += bf_lo(u.z); a5 += bf_hi(u.z); a6 += bf_lo(u.w); a7 += bf_hi(u.w);
        }
        float sc = rsqrtf((float)(full > 1 ? full : 1));
        float4 r0 = { a0 * sc, a1 * sc, a2 * sc, a3 * sc };
        float4 r1 = { a4 * sc, a5 * sc, a6 * sc, a7 * sc };
        ((float4*)out)[(size_t)node * 32 + gl * 2 + 0] = r0;  // cols 8gl..8gl+3
        ((float4*)out)[(size_t)node * 32 + gl * 2 + 1] = r1;  // cols 8gl+4..8gl+7
    }
    __syncthreads();

    // local queue overflow (expected 0)
    int lc = lovf_cnt; if (lc > LOCAL_OVF) lc = LOCAL_OVF;
    for (int k = g; k < lc; k += 16) {
        int ent = lovf[k];
        int dl = ent >> 16;
        int s  = ent & 0xFFFF;
        int full = scnt[dl] + sovf_deg[dl];
        float sc = rsqrtf((float)(full > 1 ? full : 1));
        uint4 u = f4[(size_t)s * 16 + gl];
        float* orow = out + (size_t)(bstart + dl) * D_FEAT + gl * 8;
        atomicAdd(&orow[0], bf_lo(u.x) * sc);
        atomicAdd(&orow[1], bf_hi(u.x) * sc);
        atomicAdd(&orow[2], bf_lo(u.y) * sc);
        atomicAdd(&orow[3], bf_hi(u.y) * sc);
        atomicAdd(&orow[4], bf_lo(u.z) * sc);
        atomicAdd(&orow[5], bf_hi(u.z) * sc);
        atomicAdd(&orow[6], bf_lo(u.w) * sc);
        atomicAdd(&orow[7], bf_hi(u.w) * sc);
    }
    // bin-cell overflow edges in my partition (expected 0)
    if (novf > 0) {
        for (int k = g; k < novf; k += 16) {
            int d = ovf[2 * k + 1];
            if (d >= bstart && d < bstart + NPP && d < n_nodes) {
                int s  = ovf[2 * k];
                int dl = d - bstart;
                int full = scnt[dl] + sovf_deg[dl];
                float sc = rsqrtf((float)(full > 1 ? full : 1));
                uint4 u = f4[(size_t)s * 16 + gl];
                float* orow = out + (size_t)d * D_FEAT + gl * 8;
                atomicAdd(&orow[0], bf_lo(u.x) * sc);
                atomicAdd(&orow[1], bf_hi(u.x) * sc);
                atomicAdd(&orow[2], bf_lo(u.y) * sc);
                atomicAdd(&orow[3], bf_hi(u.y) * sc);
                atomicAdd(&orow[4], bf_lo(u.z) * sc);
                atomicAdd(&orow[5], bf_hi(u.z) * sc);
                atomicAdd(&orow[6], bf_lo(u.w) * sc);
                atomicAdd(&orow[7], bf_hi(u.w) * sc);
            }
        }
    }
}

// ---------------- fallback path (fp32 atomics) ----------------

__global__ void zero_kernel(float* __restrict__ out, float* __restrict__ deg,
                            int n_out, int n_deg) {
    int i = blockIdx.x * blockDim.x + threadIdx.x;
    if (i < n_out) out[i] = 0.0f;
    if (i < n_deg) deg[i] = 0.0f;
}

__global__ void scatter_kernel(const float* __restrict__ feat,
                               const int* __restrict__ src,
                               const int* __restrict__ dst,
                               float* __restrict__ out,
                               float* __restrict__ deg,
                               int n_edges) {
    long long gid = (long long)blockIdx.x * blockDim.x + threadIdx.x;
    int e = (int)(gid >> 7);
    int f = (int)(gid & 127);
    if (e >= n_edges) return;
    int s = src[e];
    int d = dst[e];
    float v = feat[(long long)s * D_FEAT + f];
    atomicAdd(&out[(long long)d * D_FEAT + f], v);
    if (f == 0) atomicAdd(&deg[d], 1.0f);
}

__global__ void norm_kernel(float* __restrict__ out, const float* __restrict__ deg,
                            int n_out) {
    int gid = blockIdx.x * blockDim.x + threadIdx.x;
    if (gid >= n_out) return;
    int i = gid >> 7;
    float dg = fmaxf(deg[i], 1.0f);
    out[gid] = out[gid] * rsqrtf(dg);
}

extern "C" void kernel_launch(void* const* d_in, const int* in_sizes, int n_in,
                              void* d_out, int out_size, void* d_ws, size_t ws_size,
                              hipStream_t stream) {
    const float* feat = (const float*)d_in[0];
    const int*   src  = (const int*)d_in[1];
    const int*   dst  = (const int*)d_in[2];
    float* out = (float*)d_out;

    const int n_edges = in_sizes[1];
    const int n_out   = out_size;            // n_nodes * 128
    const int n_nodes = n_out / D_FEAT;

    int npart = (n_nodes + NPP - 1) / NPP;
    int nblk  = (n_edges + EPB - 1) / EPB;
    int npacks = n_out / 4;

    // ws (ints, 16B-aligned regions):
    //   ovf_cnt[4] | ovf[2*MAX_OVF] | gcnt[nblk*npart] | bins[npart*nblk*PCAP]
    //   | fbf[n_out/2]
    size_t gcnt_ints = ((size_t)nblk * npart + 3) & ~(size_t)3;
    size_t bins_ints = (size_t)npart * nblk * PCAP;     // multiple of 16
    size_t need = (4 + 2 * (size_t)MAX_OVF + gcnt_ints + bins_ints
                   + (size_t)n_out / 2) * sizeof(int);

    if (ws_size >= need && npart <= MAX_NPART && n_nodes <= 16384) {
        int* ovf_cnt = (int*)d_ws;
        int* ovf     = ovf_cnt + 4;
        int* gcnt    = ovf + 2 * MAX_OVF;
        u32* bins    = (u32*)(gcnt + gcnt_ints);
        u32* fbf     = bins + bins_ints;

        hipMemsetAsync(ovf_cnt, 0, 16, stream);
        bin_kernel<<<nblk, BIN_THREADS, 0, stream>>>(
            src, dst, feat, fbf, gcnt, ovf_cnt, ovf, bins,
            n_edges, npart, nblk, npacks);
        gather_kernel<<<npart, 256, 0, stream>>>(
            fbf, bins, gcnt, ovf_cnt, ovf, out, n_nodes, npart, nblk);
    } else {
        float* deg = (float*)d_ws;
        {
            int threads = 256;
            int blocks = (n_out + threads - 1) / threads;
            zero_kernel<<<blocks, threads, 0, stream>>>(out, deg, n_out, n_nodes);
        }
        {
            long long total = (long long)n_edges * D_FEAT;
            int threads = 256;
            int blocks = (int)((total + threads - 1) / threads);
            scatter_kernel<<<blocks, threads, 0, stream>>>(feat, src, dst, out, deg, n_edges);
        }
        {
            int threads = 256;
            int blocks = (n_out + threads - 1) / threads;
            norm_kernel<<<blocks, threads, 0, stream>>>(out, deg, n_out);
        }
    }
}